// Round 7
// baseline (164.258 us; speedup 1.0000x reference)
//
#include <hip/hip_runtime.h>

#define BB 4
#define NI 16
#define CC 3
#define HH 256
#define WW 256
#define HWSZ (HH * WW)

// ---------------------------------------------------------------------------
// Per-instance scalars, computed inline (redundantly per block; 13 broadcast
// loads). coef = instance_valid * (mode in {0,2,4} ? 1 : mode==3 ? alpha : 0).
// ---------------------------------------------------------------------------
__device__ __forceinline__ float inst_params(
    const float* __restrict__ ml, const float* __restrict__ tp,
    const float* __restrict__ al, const float* __restrict__ iv,
    int id, float th[6]) {
    float best = ml[id * 5];
    int bid = 0;
#pragma unroll
    for (int k = 1; k < 5; ++k) {
        float v = ml[id * 5 + k];
        if (v > best) { best = v; bid = k; }   // strict >: first max, like jnp.argmax
    }
    float coef = (bid == 0 || bid == 2 || bid == 4) ? 1.0f
               : (bid == 3 ? al[id] : 0.0f);
    coef *= iv[id];
#pragma unroll
    for (int k = 0; k < 6; ++k) th[k] = tp[id * 6 + k];
    return coef;
}

struct Samp {
    int o00;
    float w00, w10, w01, w11;
    bool v00, v10, v01, v11;
};

__device__ __forceinline__ Samp make_samp(const float th[6], int p) {
    const int h = p >> 8, w = p & (WW - 1);
    const float xs = (2 * w + 1) * (1.0f / WW) - 1.0f;
    const float ys = (2 * h + 1) * (1.0f / HH) - 1.0f;
    const float gx = th[0] * xs + th[1] * ys + th[2];
    const float gy = th[3] * xs + th[4] * ys + th[5];
    const float ix = gx * (0.5f * WW) + (0.5f * WW - 0.5f);
    const float iy = gy * (0.5f * HH) + (0.5f * HH - 0.5f);
    const float x0f = floorf(ix), y0f = floorf(iy);
    const float wx1 = ix - x0f, wy1 = iy - y0f;
    const float wx0 = 1.0f - wx1, wy0 = 1.0f - wy1;
    const int x0 = (int)x0f, y0 = (int)y0f;
    const bool vx0 = (unsigned)x0 < (unsigned)WW;
    const bool vx1 = (unsigned)(x0 + 1) < (unsigned)WW;
    const bool vy0 = (unsigned)y0 < (unsigned)HH;
    const bool vy1 = (unsigned)(y0 + 1) < (unsigned)HH;
    Samp s;
    s.o00 = y0 * WW + x0;
    s.v00 = vx0 && vy0; s.v10 = vx1 && vy0;
    s.v01 = vx0 && vy1; s.v11 = vx1 && vy1;
    s.w00 = wx0 * wy0;  s.w10 = wx1 * wy0;
    s.w01 = wx0 * wy1;  s.w11 = wx1 * wy1;
    return s;
}

__device__ __forceinline__ float bilerp(const float* __restrict__ src, const Samp& s) {
    const float a00 = s.v00 ? src[s.o00] : 0.0f;
    const float a10 = s.v10 ? src[s.o00 + 1] : 0.0f;
    const float a01 = s.v01 ? src[s.o00 + WW] : 0.0f;
    const float a11 = s.v11 ? src[s.o00 + WW + 1] : 0.0f;
    return s.w00 * a00 + s.w10 * a10 + s.w01 * a01 + s.w11 * a11;
}

// ---------------------------------------------------------------------------
// K1: one block per (512-pixel slab, global instance). 2 adjacent pixels per
// thread -> 32 independent gathers in flight, float2 stores. Inactive
// instances degrade to pure streaming zero-fill.
// ---------------------------------------------------------------------------
__global__ __launch_bounds__(256) void warp_inst(
    const float* __restrict__ g0,
    const float* __restrict__ m0,
    const float* __restrict__ ml,
    const float* __restrict__ tp,
    const float* __restrict__ al,
    const float* __restrict__ iv,
    float* __restrict__ out_gpi,
    float* __restrict__ out_mpi) {
    const int id = blockIdx.y;                       // 0..63
    const int p0 = blockIdx.x * 512 + threadIdx.x * 2;  // flat pixel, even

    float th[6];
    const float coef = inst_params(ml, tp, al, iv, id, th);

    float* gp = out_gpi + (size_t)id * CC * HWSZ + p0;
    float* mp = out_mpi + (size_t)id * HWSZ + p0;

    if (coef == 0.0f) {                              // block-uniform zero-fill
        const float2 z = make_float2(0.0f, 0.0f);
        *(float2*)(gp)            = z;
        *(float2*)(gp + HWSZ)     = z;
        *(float2*)(gp + 2 * HWSZ) = z;
        *(float2*)(mp)            = z;
        return;
    }

    const Samp sa = make_samp(th, p0);
    const Samp sb = make_samp(th, p0 + 1);

    const float* gsrc = g0 + (size_t)id * CC * HWSZ;
    const float* msrc = m0 + (size_t)id * HWSZ;

    float2 r0, r1, r2, rm;
    r0.x = coef * bilerp(gsrc, sa);
    r0.y = coef * bilerp(gsrc, sb);
    r1.x = coef * bilerp(gsrc + HWSZ, sa);
    r1.y = coef * bilerp(gsrc + HWSZ, sb);
    r2.x = coef * bilerp(gsrc + 2 * HWSZ, sa);
    r2.y = coef * bilerp(gsrc + 2 * HWSZ, sb);
    rm.x = coef * bilerp(msrc, sa);
    rm.y = coef * bilerp(msrc, sb);

    *(float2*)(gp)            = r0;
    *(float2*)(gp + HWSZ)     = r1;
    *(float2*)(gp + 2 * HWSZ) = r2;
    *(float2*)(mp)            = rm;
}

// ---------------------------------------------------------------------------
// K2: reduce the 16 instances (gpi/mpi L3-warm from K1) with float4 loads;
// produce g_mid / m_mid / i_base.
// ---------------------------------------------------------------------------
__global__ __launch_bounds__(128) void combine_k(
    const float* __restrict__ gpi,
    const float* __restrict__ mpi,
    const float* __restrict__ i_bg,
    float* __restrict__ out_gmid,
    float* __restrict__ out_mmid,
    float* __restrict__ out_ibase) {
    const int b = blockIdx.y;
    const int pix = (blockIdx.x * 128 + threadIdx.x) * 4;  // 16B-aligned

    float4 s0 = make_float4(0.f, 0.f, 0.f, 0.f);
    float4 s1 = s0, s2 = s0, sm = s0;
#pragma unroll
    for (int ii = 0; ii < NI; ++ii) {
        const float* gb = gpi + (size_t)(b * NI + ii) * CC * HWSZ + pix;
        const float4 a0 = *(const float4*)(gb);
        const float4 a1 = *(const float4*)(gb + HWSZ);
        const float4 a2 = *(const float4*)(gb + 2 * HWSZ);
        const float4 am = *(const float4*)(mpi + (size_t)(b * NI + ii) * HWSZ + pix);
        s0.x += a0.x; s0.y += a0.y; s0.z += a0.z; s0.w += a0.w;
        s1.x += a1.x; s1.y += a1.y; s1.z += a1.z; s1.w += a1.w;
        s2.x += a2.x; s2.y += a2.y; s2.z += a2.z; s2.w += a2.w;
        sm.x += am.x; sm.y += am.y; sm.z += am.z; sm.w += am.w;
    }
    const size_t ob = (size_t)b * CC * HWSZ + pix;
    const float4 bg0 = *(const float4*)(i_bg + ob);
    const float4 bg1 = *(const float4*)(i_bg + ob + HWSZ);
    const float4 bg2 = *(const float4*)(i_bg + ob + 2 * HWSZ);

    *(float4*)(out_gmid + ob)            = s0;
    *(float4*)(out_gmid + ob + HWSZ)     = s1;
    *(float4*)(out_gmid + ob + 2 * HWSZ) = s2;
    *(float4*)(out_ibase + ob) =
        make_float4(s0.x + bg0.x, s0.y + bg0.y, s0.z + bg0.z, s0.w + bg0.w);
    *(float4*)(out_ibase + ob + HWSZ) =
        make_float4(s1.x + bg1.x, s1.y + bg1.y, s1.z + bg1.z, s1.w + bg1.w);
    *(float4*)(out_ibase + ob + 2 * HWSZ) =
        make_float4(s2.x + bg2.x, s2.y + bg2.y, s2.z + bg2.z, s2.w + bg2.w);
    *(float4*)(out_mmid + (size_t)b * HWSZ + pix) =
        make_float4(fminf(fmaxf(sm.x, 0.f), 1.f), fminf(fmaxf(sm.y, 0.f), 1.f),
                    fminf(fmaxf(sm.z, 0.f), 1.f), fminf(fmaxf(sm.w, 0.f), 1.f));
}

extern "C" void kernel_launch(void* const* d_in, const int* in_sizes, int n_in,
                              void* d_out, int out_size, void* d_ws, size_t ws_size,
                              hipStream_t stream) {
    const float* g0          = (const float*)d_in[0];
    const float* m0          = (const float*)d_in[1];
    const float* mode_logits = (const float*)d_in[2];
    const float* tp          = (const float*)d_in[3];
    const float* alpha       = (const float*)d_in[4];
    const float* iv          = (const float*)d_in[5];
    const float* i_bg        = (const float*)d_in[6];

    float* out       = (float*)d_out;
    float* out_gpi   = out;                                        // [B,NI,C,H,W]
    float* out_mpi   = out_gpi  + (size_t)BB * NI * CC * HWSZ;     // [B,NI,1,H,W]
    float* out_gmid  = out_mpi  + (size_t)BB * NI * HWSZ;          // [B,C,H,W]
    float* out_mmid  = out_gmid + (size_t)BB * CC * HWSZ;          // [B,1,H,W]
    float* out_ibase = out_mmid + (size_t)BB * HWSZ;               // [B,C,H,W]

    dim3 grid1(HWSZ / 512, BB * NI);                               // 128 x 64
    warp_inst<<<grid1, 256, 0, stream>>>(g0, m0, mode_logits, tp, alpha, iv,
                                         out_gpi, out_mpi);

    dim3 grid2(HWSZ / 4 / 128, BB);                                // 128 x 4
    combine_k<<<grid2, 128, 0, stream>>>(out_gpi, out_mpi, i_bg,
                                         out_gmid, out_mmid, out_ibase);
}

// Round 8
// 155.782 us; speedup vs baseline: 1.0544x; 1.0544x over previous
//
#include <hip/hip_runtime.h>

#define BB 4
#define NI 16
#define CC 3
#define HH 256
#define WW 256
#define HWSZ (HH * WW)

// ---------------------------------------------------------------------------
// Per-instance scalars, computed inline (13 scalar loads, block-uniform id).
// coef = instance_valid * (mode in {0,2,4} ? 1 : mode==3 ? alpha : 0).
// ---------------------------------------------------------------------------
__device__ __forceinline__ float inst_params(
    const float* __restrict__ ml, const float* __restrict__ tp,
    const float* __restrict__ al, const float* __restrict__ iv,
    int id, float th[6]) {
    float best = ml[id * 5];
    int bid = 0;
#pragma unroll
    for (int k = 1; k < 5; ++k) {
        float v = ml[id * 5 + k];
        if (v > best) { best = v; bid = k; }   // strict >: first max, like jnp.argmax
    }
    float coef = (bid == 0 || bid == 2 || bid == 4) ? 1.0f
               : (bid == 3 ? al[id] : 0.0f);
    coef *= iv[id];
#pragma unroll
    for (int k = 0; k < 6; ++k) th[k] = tp[id * 6 + k];
    return coef;
}

// Masked-weight sampler: weights carry the validity (zero outside), offsets
// are clamped in-range so all loads are unconditional.
struct Samp {
    int o00, o10, o01, o11;
    float w00, w10, w01, w11;
};

__device__ __forceinline__ Samp make_samp(const float th[6], int p) {
    const int h = p >> 8, w = p & (WW - 1);
    const float xs = (2 * w + 1) * (1.0f / WW) - 1.0f;
    const float ys = (2 * h + 1) * (1.0f / HH) - 1.0f;
    const float gx = th[0] * xs + th[1] * ys + th[2];
    const float gy = th[3] * xs + th[4] * ys + th[5];
    const float ix = gx * (0.5f * WW) + (0.5f * WW - 0.5f);
    const float iy = gy * (0.5f * HH) + (0.5f * HH - 0.5f);
    const float x0f = floorf(ix), y0f = floorf(iy);
    const float wx1 = ix - x0f, wy1 = iy - y0f;
    const float wx0 = 1.0f - wx1, wy0 = 1.0f - wy1;
    const int x0 = (int)x0f, y0 = (int)y0f;
    const int x1 = x0 + 1, y1 = y0 + 1;
    const float wx0v = ((unsigned)x0 < (unsigned)WW) ? wx0 : 0.0f;
    const float wx1v = ((unsigned)x1 < (unsigned)WW) ? wx1 : 0.0f;
    const float wy0v = ((unsigned)y0 < (unsigned)HH) ? wy0 : 0.0f;
    const float wy1v = ((unsigned)y1 < (unsigned)HH) ? wy1 : 0.0f;
    const int x0c = min(max(x0, 0), WW - 1), x1c = min(max(x1, 0), WW - 1);
    const int y0c = min(max(y0, 0), HH - 1), y1c = min(max(y1, 0), HH - 1);
    Samp s;
    s.o00 = y0c * WW + x0c; s.o10 = y0c * WW + x1c;
    s.o01 = y1c * WW + x0c; s.o11 = y1c * WW + x1c;
    s.w00 = wx0v * wy0v; s.w10 = wx1v * wy0v;
    s.w01 = wx0v * wy1v; s.w11 = wx1v * wy1v;
    return s;
}

__device__ __forceinline__ float bilerp(const float* __restrict__ src, const Samp& s) {
    return s.w00 * src[s.o00] + s.w10 * src[s.o10]
         + s.w01 * src[s.o01] + s.w11 * src[s.o11];
}

// ---------------------------------------------------------------------------
// K1: one block per (2-row slab, global instance). Each thread handles pixels
// p and p+256 (same column, adjacent rows) -> all 32 gathers lane-contiguous
// AND independent. Inactive instances degrade to streaming zero-fill.
// ---------------------------------------------------------------------------
__global__ __launch_bounds__(256) void warp_inst(
    const float* __restrict__ g0,
    const float* __restrict__ m0,
    const float* __restrict__ ml,
    const float* __restrict__ tp,
    const float* __restrict__ al,
    const float* __restrict__ iv,
    float* __restrict__ out_gpi,
    float* __restrict__ out_mpi) {
    const int id = blockIdx.y;                         // 0..63
    const int p0 = blockIdx.x * 512 + threadIdx.x;     // row pair: p0, p0+256

    float th[6];
    const float coef = inst_params(ml, tp, al, iv, id, th);

    float* gp = out_gpi + (size_t)id * CC * HWSZ + p0;
    float* mp = out_mpi + (size_t)id * HWSZ + p0;

    if (coef == 0.0f) {                                // block-uniform zero-fill
        gp[0] = 0.0f;            gp[WW] = 0.0f;
        gp[HWSZ] = 0.0f;         gp[HWSZ + WW] = 0.0f;
        gp[2 * HWSZ] = 0.0f;     gp[2 * HWSZ + WW] = 0.0f;
        mp[0] = 0.0f;            mp[WW] = 0.0f;
        return;
    }

    const Samp sa = make_samp(th, p0);
    const Samp sb = make_samp(th, p0 + WW);

    const float* gsrc = g0 + (size_t)id * CC * HWSZ;
    const float* msrc = m0 + (size_t)id * HWSZ;

    const float v0a = coef * bilerp(gsrc, sa);
    const float v0b = coef * bilerp(gsrc, sb);
    const float v1a = coef * bilerp(gsrc + HWSZ, sa);
    const float v1b = coef * bilerp(gsrc + HWSZ, sb);
    const float v2a = coef * bilerp(gsrc + 2 * HWSZ, sa);
    const float v2b = coef * bilerp(gsrc + 2 * HWSZ, sb);
    const float vma = coef * bilerp(msrc, sa);
    const float vmb = coef * bilerp(msrc, sb);

    gp[0] = v0a;            gp[WW] = v0b;
    gp[HWSZ] = v1a;         gp[HWSZ + WW] = v1b;
    gp[2 * HWSZ] = v2a;     gp[2 * HWSZ + WW] = v2b;
    mp[0] = vma;            mp[WW] = vmb;
}

// ---------------------------------------------------------------------------
// K2: reduce the 16 instances (gpi/mpi L3-warm from K1) with float4 loads;
// produce g_mid / m_mid / i_base.
// ---------------------------------------------------------------------------
__global__ __launch_bounds__(128) void combine_k(
    const float* __restrict__ gpi,
    const float* __restrict__ mpi,
    const float* __restrict__ i_bg,
    float* __restrict__ out_gmid,
    float* __restrict__ out_mmid,
    float* __restrict__ out_ibase) {
    const int b = blockIdx.y;
    const int pix = (blockIdx.x * 128 + threadIdx.x) * 4;  // 16B-aligned

    float4 s0 = make_float4(0.f, 0.f, 0.f, 0.f);
    float4 s1 = s0, s2 = s0, sm = s0;
#pragma unroll
    for (int ii = 0; ii < NI; ++ii) {
        const float* gb = gpi + (size_t)(b * NI + ii) * CC * HWSZ + pix;
        const float4 a0 = *(const float4*)(gb);
        const float4 a1 = *(const float4*)(gb + HWSZ);
        const float4 a2 = *(const float4*)(gb + 2 * HWSZ);
        const float4 am = *(const float4*)(mpi + (size_t)(b * NI + ii) * HWSZ + pix);
        s0.x += a0.x; s0.y += a0.y; s0.z += a0.z; s0.w += a0.w;
        s1.x += a1.x; s1.y += a1.y; s1.z += a1.z; s1.w += a1.w;
        s2.x += a2.x; s2.y += a2.y; s2.z += a2.z; s2.w += a2.w;
        sm.x += am.x; sm.y += am.y; sm.z += am.z; sm.w += am.w;
    }
    const size_t ob = (size_t)b * CC * HWSZ + pix;
    const float4 bg0 = *(const float4*)(i_bg + ob);
    const float4 bg1 = *(const float4*)(i_bg + ob + HWSZ);
    const float4 bg2 = *(const float4*)(i_bg + ob + 2 * HWSZ);

    *(float4*)(out_gmid + ob)            = s0;
    *(float4*)(out_gmid + ob + HWSZ)     = s1;
    *(float4*)(out_gmid + ob + 2 * HWSZ) = s2;
    *(float4*)(out_ibase + ob) =
        make_float4(s0.x + bg0.x, s0.y + bg0.y, s0.z + bg0.z, s0.w + bg0.w);
    *(float4*)(out_ibase + ob + HWSZ) =
        make_float4(s1.x + bg1.x, s1.y + bg1.y, s1.z + bg1.z, s1.w + bg1.w);
    *(float4*)(out_ibase + ob + 2 * HWSZ) =
        make_float4(s2.x + bg2.x, s2.y + bg2.y, s2.z + bg2.z, s2.w + bg2.w);
    *(float4*)(out_mmid + (size_t)b * HWSZ + pix) =
        make_float4(fminf(fmaxf(sm.x, 0.f), 1.f), fminf(fmaxf(sm.y, 0.f), 1.f),
                    fminf(fmaxf(sm.z, 0.f), 1.f), fminf(fmaxf(sm.w, 0.f), 1.f));
}

extern "C" void kernel_launch(void* const* d_in, const int* in_sizes, int n_in,
                              void* d_out, int out_size, void* d_ws, size_t ws_size,
                              hipStream_t stream) {
    const float* g0          = (const float*)d_in[0];
    const float* m0          = (const float*)d_in[1];
    const float* mode_logits = (const float*)d_in[2];
    const float* tp          = (const float*)d_in[3];
    const float* alpha       = (const float*)d_in[4];
    const float* iv          = (const float*)d_in[5];
    const float* i_bg        = (const float*)d_in[6];

    float* out       = (float*)d_out;
    float* out_gpi   = out;                                        // [B,NI,C,H,W]
    float* out_mpi   = out_gpi  + (size_t)BB * NI * CC * HWSZ;     // [B,NI,1,H,W]
    float* out_gmid  = out_mpi  + (size_t)BB * NI * HWSZ;          // [B,C,H,W]
    float* out_mmid  = out_gmid + (size_t)BB * CC * HWSZ;          // [B,1,H,W]
    float* out_ibase = out_mmid + (size_t)BB * HWSZ;               // [B,C,H,W]

    dim3 grid1(HWSZ / 512, BB * NI);                               // 128 x 64
    warp_inst<<<grid1, 256, 0, stream>>>(g0, m0, mode_logits, tp, alpha, iv,
                                         out_gpi, out_mpi);

    dim3 grid2(HWSZ / 4 / 128, BB);                                // 128 x 4
    combine_k<<<grid2, 128, 0, stream>>>(out_gpi, out_mpi, i_bg,
                                         out_gmid, out_mmid, out_ibase);
}